// Round 13
// baseline (85.545 us; speedup 1.0000x reference)
//
#include <hip/hip_runtime.h>

// CategoryDense: out[b,c,o] = sum_i x[b,c,i] * kernel[c,i,o] + bias[c,o]
// B=8192, C=64, IN=64, OUT=64, fp32 in/out. bf16 MFMA (swapped operands).
//
// R13 = R12 + occupancy push:
//  - repack LDS halved 32KB -> 16KB (per-wave 4KB, each p-pass repacked in
//    two 16-row halves; buffer reused sequentially, still zero barriers)
//  - __launch_bounds__(256,6): VGPR cap 85 (kernel uses ~60; R9's spill was
//    64-cap vs ~96-live) -> 6 blocks/CU x 4 waves = 24 waves/CU vs ~10.
//  Epilogue keeps R12's full-line nontemporal stores (WRITE=131MB proven).
//  K1 (transpose_k): kernel -> g_kt[c][o][i] bf16, unchanged.

constexpr int C_   = 64;
constexpr int IN_  = 64;
constexpr int OUT_ = 64;
constexpr int BT   = 256;

typedef __attribute__((ext_vector_type(8))) short bf16x8;
typedef __attribute__((ext_vector_type(4))) short s16x4;
typedef __attribute__((ext_vector_type(4))) float f32x4;

__device__ unsigned short g_kt[C_ * OUT_ * IN_];   // 512 KB: kT[c][o][i] bf16

__device__ __forceinline__ short f2bf(float f) {
    union { float f; unsigned u; } v; v.f = f;
    unsigned r = v.u + 0x7FFF + ((v.u >> 16) & 1);   // RNE
    return (short)(r >> 16);
}

__device__ __forceinline__ bf16x8 cvt8(f32x4 lo, f32x4 hi) {
    bf16x8 r;
    #pragma unroll
    for (int e = 0; e < 4; ++e) {
        r[e]     = f2bf(lo[e]);
        r[4 + e] = f2bf(hi[e]);
    }
    return r;
}

__global__ __launch_bounds__(256)
void transpose_k(const float* __restrict__ k) {
    __shared__ unsigned short ks[IN_ * OUT_];   // 8 KB bf16 [i][o]
    const int tid = threadIdx.x;
    const int c   = blockIdx.x;

    #pragma unroll
    for (int it = 0; it < 4; ++it) {
        int p = tid + it * 256;
        f32x4 v = *(const f32x4*)(k + (size_t)c * (IN_ * OUT_) + (size_t)p * 4);
        s16x4 w;
        #pragma unroll
        for (int e = 0; e < 4; ++e) w[e] = f2bf(v[e]);
        *(s16x4*)(&ks[p * 4]) = w;
    }
    __syncthreads();

    const int o   = tid >> 2;
    const int is0 = (tid & 3) * 16;
    short tmp[16];
    #pragma unroll
    for (int j = 0; j < 16; ++j)
        tmp[j] = (short)ks[(is0 + j) * OUT_ + o];
    unsigned short* dst = &g_kt[(size_t)c * (OUT_ * IN_) + o * IN_ + is0];
    *(bf16x8*)(dst)     = *(const bf16x8*)(&tmp[0]);
    *(bf16x8*)(dst + 8) = *(const bf16x8*)(&tmp[8]);
}

__global__ __launch_bounds__(256, 6)
void cat_dense_mfma9(const float* __restrict__ x,
                     const float* __restrict__ bias,
                     float* __restrict__ out) {
    __shared__ float rp[4][16 * 64];   // 16 KB: per-wave 4 KB repack buffer

    const int tid  = threadIdx.x;
    const int wv   = tid >> 6;
    const int lane = tid & 63;
    const int c    = blockIdx.x & 63;
    const long bBase = (long)(blockIdx.x >> 6) * BT;

    const int lrow = lane & 15;   // B col = batch row; A row = out channel
    const int lkg  = lane >> 4;   // K-octet select; C row-group

    // ---- xT B-fragments direct from global (issue first, long latency) ----
    const long rw = bBase + wv * 64;
    bf16x8 af[2][2][2];   // [p][mt][ksi]
    #pragma unroll
    for (int p = 0; p < 2; ++p)
      #pragma unroll
      for (int mt = 0; mt < 2; ++mt)
        #pragma unroll
        for (int ksi = 0; ksi < 2; ++ksi) {
            const float* xp = x
                + (size_t)(rw + p * 32 + mt * 16 + lrow) * (C_ * IN_)
                + (size_t)c * IN_ + ksi * 32 + lkg * 8;
            f32x4 lo = *(const f32x4*)xp;
            f32x4 hi = *(const f32x4*)(xp + 4);
            af[p][mt][ksi] = cvt8(lo, hi);
        }

    // ---- kT A-fragments: contiguous 16B loads, L2-resident ----
    bf16x8 kb[4][2];
    #pragma unroll
    for (int nt = 0; nt < 4; ++nt)
      #pragma unroll
      for (int ksi = 0; ksi < 2; ++ksi)
        kb[nt][ksi] = *(const bf16x8*)(
            &g_kt[(size_t)c * (OUT_ * IN_) + (nt * 16 + lrow) * IN_
                  + ksi * 32 + lkg * 8]);

    // bias: lane's 4 consecutive output cols per nt (o = nt*16 + lkg*4 ..+4)
    f32x4 bv[4];
    #pragma unroll
    for (int nt = 0; nt < 4; ++nt)
        bv[nt] = *(const f32x4*)(bias + (size_t)c * OUT_ + nt * 16 + lkg * 4);

    float* rpw = &rp[wv][0];

    // ---- two M=32 passes: MFMA -> per-16-row LDS repack -> full-line nt ----
    #pragma unroll
    for (int p = 0; p < 2; ++p) {
        f32x4 acc[2][4];
        #pragma unroll
        for (int mt = 0; mt < 2; ++mt)
          #pragma unroll
          for (int nt = 0; nt < 4; ++nt)
            acc[mt][nt] = (f32x4){0.f, 0.f, 0.f, 0.f};

        #pragma unroll
        for (int ksi = 0; ksi < 2; ++ksi)
          #pragma unroll
          for (int mt = 0; mt < 2; ++mt)
            #pragma unroll
            for (int nt = 0; nt < 4; ++nt)
                acc[mt][nt] = __builtin_amdgcn_mfma_f32_16x16x32_bf16(
                                  kb[nt][ksi], af[p][mt][ksi],
                                  acc[mt][nt], 0, 0, 0);

        // per mt-half: 16 rows through the 4KB wave buffer (reused; RAW
        // within the same wave — no barrier needed)
        #pragma unroll
        for (int mt = 0; mt < 2; ++mt) {
            // write: cell (row=lrow, o=nt*16+lkg*4+e) at word
            //   lrow*64 + ((nt*16+lkg*4) ^ (lrow<<2)) + e
            #pragma unroll
            for (int nt = 0; nt < 4; ++nt) {
                int off = ((nt * 16 + lkg * 4) ^ (lrow << 2));
                *(f32x4*)(&rpw[lrow * 64 + off]) = acc[mt][nt] + bv[nt];
            }

            // read back + full-line nt stores: instr j covers 4 rows x 256B
            const int m = lane & 15;    // 16B chunk within row
            const int t = lane >> 4;    // row within group of 4
            #pragma unroll
            for (int j = 0; j < 4; ++j) {
                int bl   = j * 4 + t;                     // row 0..15
                int offr = ((m ^ bl) << 2);
                f32x4 v = *(const f32x4*)(&rpw[bl * 64 + offr]);
                size_t ob = (size_t)(rw + p * 32 + mt * 16 + bl) * (C_ * OUT_)
                          + (size_t)c * OUT_ + m * 4;
                __builtin_nontemporal_store(v, (f32x4*)(out + ob));
            }
        }
    }
}

extern "C" void kernel_launch(void* const* d_in, const int* in_sizes, int n_in,
                              void* d_out, int out_size, void* d_ws, size_t ws_size,
                              hipStream_t stream) {
    const float* x    = (const float*)d_in[0];
    const float* k    = (const float*)d_in[1];
    const float* bias = (const float*)d_in[2];
    float* out        = (float*)d_out;

    transpose_k<<<dim3(C_), 256, 0, stream>>>(k);

    const int B     = in_sizes[0] / (C_ * IN_);   // 8192
    const int tiles = B / BT;                     // 32
    dim3 grid(64 * tiles);                        // 2048: c = blk & 63
    cat_dense_mfma9<<<grid, 256, 0, stream>>>(x, bias, out);
}

// Round 14
// 70.765 us; speedup vs baseline: 1.2089x; 1.2089x over previous
//
#include <hip/hip_runtime.h>

// CategoryDense: out[b,c,o] = sum_i x[b,c,i] * kernel[c,i,o] + bias[c,o]
// B=8192, C=64, IN=64, OUT=64, fp32 in/out. bf16 MFMA (swapped operands).
//
// R14: occupancy via SMALL REGISTER FOOTPRINT (not via caps on a big tile —
// R9/R13 both spilled because the unified VGPR+AGPR live set exceeded the
// cap; AGPR accumulators don't show in VGPR_Count).
//  - wave tile = 32 batches x 64 outs, out-halves computed sequentially:
//    af 16 reg + kb 8 (per h,ksi) + acc 16 (per half) ~= 56 unified live
//  - __launch_bounds__(256,8): 8 waves/SIMD, ZERO LDS, ZERO barriers
//  - plain f32x4 stores (R6/R11 evidence: L2 merges scattered 16B stores to
//    exactly 131MB); no nt, no repack
//  - block = 128 batches, grid = 4096
//  K1 (transpose_k): kernel -> g_kt[c][o][i] bf16, unchanged.

constexpr int C_   = 64;
constexpr int IN_  = 64;
constexpr int OUT_ = 64;
constexpr int BT   = 128;   // batches per block (4 waves x 32)

typedef __attribute__((ext_vector_type(8))) short bf16x8;
typedef __attribute__((ext_vector_type(4))) short s16x4;
typedef __attribute__((ext_vector_type(4))) float f32x4;

__device__ unsigned short g_kt[C_ * OUT_ * IN_];   // 512 KB: kT[c][o][i] bf16

__device__ __forceinline__ short f2bf(float f) {
    union { float f; unsigned u; } v; v.f = f;
    unsigned r = v.u + 0x7FFF + ((v.u >> 16) & 1);   // RNE
    return (short)(r >> 16);
}

__device__ __forceinline__ bf16x8 cvt8(f32x4 lo, f32x4 hi) {
    bf16x8 r;
    #pragma unroll
    for (int e = 0; e < 4; ++e) {
        r[e]     = f2bf(lo[e]);
        r[4 + e] = f2bf(hi[e]);
    }
    return r;
}

__global__ __launch_bounds__(256)
void transpose_k(const float* __restrict__ k) {
    __shared__ unsigned short ks[IN_ * OUT_];   // 8 KB bf16 [i][o]
    const int tid = threadIdx.x;
    const int c   = blockIdx.x;

    #pragma unroll
    for (int it = 0; it < 4; ++it) {
        int p = tid + it * 256;
        f32x4 v = *(const f32x4*)(k + (size_t)c * (IN_ * OUT_) + (size_t)p * 4);
        s16x4 w;
        #pragma unroll
        for (int e = 0; e < 4; ++e) w[e] = f2bf(v[e]);
        *(s16x4*)(&ks[p * 4]) = w;
    }
    __syncthreads();

    const int o   = tid >> 2;
    const int is0 = (tid & 3) * 16;
    short tmp[16];
    #pragma unroll
    for (int j = 0; j < 16; ++j)
        tmp[j] = (short)ks[(is0 + j) * OUT_ + o];
    unsigned short* dst = &g_kt[(size_t)c * (OUT_ * IN_) + o * IN_ + is0];
    *(bf16x8*)(dst)     = *(const bf16x8*)(&tmp[0]);
    *(bf16x8*)(dst + 8) = *(const bf16x8*)(&tmp[8]);
}

__global__ __launch_bounds__(256, 8)
void cat_dense_mfma10(const float* __restrict__ x,
                      const float* __restrict__ bias,
                      float* __restrict__ out) {
    const int tid  = threadIdx.x;
    const int wv   = tid >> 6;
    const int lane = tid & 63;
    const int c    = blockIdx.x & 63;
    const long bBase = (long)(blockIdx.x >> 6) * BT;

    const int lrow = lane & 15;   // B col = batch row; A row = out channel
    const int lkg  = lane >> 4;   // K-octet select; C row-group

    const long rw = bBase + wv * 32;   // this wave's 32 batch rows

    // ---- xT B-fragments direct from global (8x 16B loads, issue first) ----
    bf16x8 af[2][2];   // [mt][ksi], 16 regs
    #pragma unroll
    for (int mt = 0; mt < 2; ++mt)
      #pragma unroll
      for (int ksi = 0; ksi < 2; ++ksi) {
          const float* xp = x
              + (size_t)(rw + mt * 16 + lrow) * (C_ * IN_)
              + (size_t)c * IN_ + ksi * 32 + lkg * 8;
          f32x4 lo = *(const f32x4*)xp;
          f32x4 hi = *(const f32x4*)(xp + 4);
          af[mt][ksi] = cvt8(lo, hi);
      }

    // ---- two out-halves of 32 channels each ----
    #pragma unroll
    for (int h = 0; h < 2; ++h) {
        f32x4 acc[2][2];   // [mt][nt2], 16 regs
        #pragma unroll
        for (int mt = 0; mt < 2; ++mt)
          #pragma unroll
          for (int nt2 = 0; nt2 < 2; ++nt2)
            acc[mt][nt2] = (f32x4){0.f, 0.f, 0.f, 0.f};

        #pragma unroll
        for (int ksi = 0; ksi < 2; ++ksi) {
            bf16x8 kb[2];   // 8 regs, live only within this ksi
            #pragma unroll
            for (int nt2 = 0; nt2 < 2; ++nt2)
                kb[nt2] = *(const bf16x8*)(
                    &g_kt[(size_t)c * (OUT_ * IN_)
                          + (h * 32 + nt2 * 16 + lrow) * IN_
                          + ksi * 32 + lkg * 8]);
            #pragma unroll
            for (int mt = 0; mt < 2; ++mt)
              #pragma unroll
              for (int nt2 = 0; nt2 < 2; ++nt2)
                acc[mt][nt2] = __builtin_amdgcn_mfma_f32_16x16x32_bf16(
                                   kb[nt2], af[mt][ksi], acc[mt][nt2], 0, 0, 0);
        }

        // bias + plain f32x4 stores (L2 merges to full lines; R6/R11: 131MB)
        #pragma unroll
        for (int nt2 = 0; nt2 < 2; ++nt2) {
            f32x4 bv = *(const f32x4*)(bias + (size_t)c * OUT_
                                       + h * 32 + nt2 * 16 + lkg * 4);
            #pragma unroll
            for (int mt = 0; mt < 2; ++mt) {
                size_t ob = (size_t)(rw + mt * 16 + lrow) * (C_ * OUT_)
                          + (size_t)c * OUT_ + h * 32 + nt2 * 16 + lkg * 4;
                f32x4 o = acc[mt][nt2] + bv;
                *(f32x4*)(out + ob) = o;
            }
        }
    }
}

extern "C" void kernel_launch(void* const* d_in, const int* in_sizes, int n_in,
                              void* d_out, int out_size, void* d_ws, size_t ws_size,
                              hipStream_t stream) {
    const float* x    = (const float*)d_in[0];
    const float* k    = (const float*)d_in[1];
    const float* bias = (const float*)d_in[2];
    float* out        = (float*)d_out;

    transpose_k<<<dim3(C_), 256, 0, stream>>>(k);

    const int B     = in_sizes[0] / (C_ * IN_);   // 8192
    const int tiles = B / BT;                     // 64
    dim3 grid(64 * tiles);                        // 4096: c = blk & 63
    cat_dense_mfma10<<<grid, 256, 0, stream>>>(x, bias, out);
}

// Round 15
// 46.728 us; speedup vs baseline: 1.8307x; 1.5144x over previous
//
#include <hip/hip_runtime.h>

// CategoryDense: out[b,c,o] = sum_i x[b,c,i] * kernel[c,i,o] + bias[c,o]
// B=8192, C=64, IN=64, OUT=64, fp32 in/out. bf16 MFMA (swapped operands).
//
// R15 = R12 body, single kernel (transpose_k launch removed):
//  - kT A-fragments built directly from original k[c][i][o] via 64 scalar
//    dword loads + cvt per thread (k[c]=16KB L2-resident; hidden under x)
//  - x B-frags direct global->reg (R4/R11 proven FETCH=66MB)
//  - epilogue: per-wave LDS repack -> full-line (4 rows x 256B) nontemporal
//    stores (R12 proven: WRITE=131MB, preserves x in L3 across replays)
//  - BT=256, 4 waves, grid=2048, launch_bounds(256,4) (R9/R13 lesson:
//    never cap below unified VGPR+AGPR live set ~116)

constexpr int C_   = 64;
constexpr int IN_  = 64;
constexpr int OUT_ = 64;
constexpr int BT   = 256;

typedef __attribute__((ext_vector_type(8))) short bf16x8;
typedef __attribute__((ext_vector_type(4))) float f32x4;

__device__ __forceinline__ short f2bf(float f) {
    union { float f; unsigned u; } v; v.f = f;
    unsigned r = v.u + 0x7FFF + ((v.u >> 16) & 1);   // RNE
    return (short)(r >> 16);
}

__device__ __forceinline__ bf16x8 cvt8(f32x4 lo, f32x4 hi) {
    bf16x8 r;
    #pragma unroll
    for (int e = 0; e < 4; ++e) {
        r[e]     = f2bf(lo[e]);
        r[4 + e] = f2bf(hi[e]);
    }
    return r;
}

__global__ __launch_bounds__(256, 4)
void cat_dense_mfma11(const float* __restrict__ x,
                      const float* __restrict__ k,
                      const float* __restrict__ bias,
                      float* __restrict__ out) {
    __shared__ float rp[4][32 * 64];   // 32 KB: per-wave 8 KB repack buffer

    const int tid  = threadIdx.x;
    const int wv   = tid >> 6;
    const int lane = tid & 63;
    const int c    = blockIdx.x & 63;
    const long bBase = (long)(blockIdx.x >> 6) * BT;

    const int lrow = lane & 15;   // B col = batch row; A row = out channel
    const int lkg  = lane >> 4;   // K-octet select; C row-group

    // ---- xT B-fragments direct from global (HBM latency — issue first) ----
    const long rw = bBase + wv * 64;
    bf16x8 af[2][2][2];   // [p][mt][ksi]
    #pragma unroll
    for (int p = 0; p < 2; ++p)
      #pragma unroll
      for (int mt = 0; mt < 2; ++mt)
        #pragma unroll
        for (int ksi = 0; ksi < 2; ++ksi) {
            const float* xp = x
                + (size_t)(rw + p * 32 + mt * 16 + lrow) * (C_ * IN_)
                + (size_t)c * IN_ + ksi * 32 + lkg * 8;
            f32x4 lo = *(const f32x4*)xp;
            f32x4 hi = *(const f32x4*)(xp + 4);
            af[p][mt][ksi] = cvt8(lo, hi);
        }

    // ---- kT A-fragments direct from original k layout (L2-resident) ----
    // A[row=o=nt*16+lrow][k=i=ksi*32+lkg*8+j] = k[c][i][o]
    const float* kc = k + (size_t)c * (IN_ * OUT_);
    bf16x8 kb[4][2];
    #pragma unroll
    for (int nt = 0; nt < 4; ++nt)
      #pragma unroll
      for (int ksi = 0; ksi < 2; ++ksi) {
        union { bf16x8 v; short s[8]; } b;
        #pragma unroll
        for (int j = 0; j < 8; ++j)
            b.s[j] = f2bf(kc[(ksi * 32 + lkg * 8 + j) * OUT_ + nt * 16 + lrow]);
        kb[nt][ksi] = b.v;
      }

    // bias: lane's 4 consecutive output cols per nt (o = nt*16 + lkg*4 ..+4)
    f32x4 bv[4];
    #pragma unroll
    for (int nt = 0; nt < 4; ++nt)
        bv[nt] = *(const f32x4*)(bias + (size_t)c * OUT_ + nt * 16 + lkg * 4);

    float* rpw = &rp[wv][0];

    // ---- two M=32 passes: MFMA -> LDS repack -> full-line nt stores ----
    #pragma unroll
    for (int p = 0; p < 2; ++p) {
        f32x4 acc[2][4];
        #pragma unroll
        for (int mt = 0; mt < 2; ++mt)
          #pragma unroll
          for (int nt = 0; nt < 4; ++nt)
            acc[mt][nt] = (f32x4){0.f, 0.f, 0.f, 0.f};

        #pragma unroll
        for (int ksi = 0; ksi < 2; ++ksi)
          #pragma unroll
          for (int mt = 0; mt < 2; ++mt)
            #pragma unroll
            for (int nt = 0; nt < 4; ++nt)
                acc[mt][nt] = __builtin_amdgcn_mfma_f32_16x16x32_bf16(
                                  kb[nt][ksi], af[p][mt][ksi],
                                  acc[mt][nt], 0, 0, 0);

        // acc(+bias) -> LDS, XOR-swizzled within each 64-word row
        #pragma unroll
        for (int mt = 0; mt < 2; ++mt) {
            int bl = mt * 16 + lrow;
            #pragma unroll
            for (int nt = 0; nt < 4; ++nt) {
                int off = ((nt * 16 + lkg * 4) ^ (lrow << 2));
                *(f32x4*)(&rpw[bl * 64 + off]) = acc[mt][nt] + bv[nt];
            }
        }

        // read back (matching unswizzle): instr j covers 4 rows x 256B full
        // lines -> nontemporal store (evict-first, no partial-line writeback)
        const int m = lane & 15;    // 16B chunk within row
        const int t = lane >> 4;    // row within group of 4
        #pragma unroll
        for (int j = 0; j < 8; ++j) {
            int bl   = j * 4 + t;
            int offr = (m << 2) ^ ((bl & 15) << 2);
            f32x4 v = *(const f32x4*)(&rpw[bl * 64 + offr]);
            size_t ob = (size_t)(rw + p * 32 + bl) * (C_ * OUT_)
                      + (size_t)c * OUT_ + m * 4;
            __builtin_nontemporal_store(v, (f32x4*)(out + ob));
        }
    }
}

extern "C" void kernel_launch(void* const* d_in, const int* in_sizes, int n_in,
                              void* d_out, int out_size, void* d_ws, size_t ws_size,
                              hipStream_t stream) {
    const float* x    = (const float*)d_in[0];
    const float* k    = (const float*)d_in[1];
    const float* bias = (const float*)d_in[2];
    float* out        = (float*)d_out;

    const int B     = in_sizes[0] / (C_ * IN_);   // 8192
    const int tiles = B / BT;                     // 32
    dim3 grid(64 * tiles);                        // 2048: c = blk & 63
    cat_dense_mfma11<<<grid, 256, 0, stream>>>(x, k, bias, out);
}